// Round 12
// baseline (251.950 us; speedup 1.0000x reference)
//
#include <hip/hip_runtime.h>
#include <hip/hip_bf16.h>

// ---------------------------------------------------------------------------
// GraphAutoEncoder: 4x GCNConv + mean-pool + repeat, all f32.
// R1: hierarchical scan. R2: int2 payload, vector-per-node gathers.
// R3: binned CSR fill. R4: dec1 fused via ZW3 table. R5: count pass gone.
// R6: g packed in ew.x; W4 fused into dec1. R7: dec1 gathers z from global.
// R8: shfl-broadcast edge loops. R9: weights from global (L1), W2 fused in l1.
// R10: pooling linear -> h2/pool deleted; zagg edge-major z-sum accumulation.
// R11: dense phases register-blocked (weight column in VGPRs amortized over
//      8 outputs; activations via broadcast float4 LDS reads, padded strides)
//      -- R10 post-mortem: dec1v3/l1w2 phase-B was issue-bound at 2 loads/FMA
//      (~23 us of pure instruction issue in dec1v3's B phases alone).
// ---------------------------------------------------------------------------

constexpr int BSZ_LOG = 9;                 // bucket = 512 dst nodes
constexpr int BSZ     = 1 << BSZ_LOG;
constexpr int NBMAX   = 256;               // max buckets (n <= 128K)
constexpr int ECHUNK  = 8192;              // edges per binfill block
constexpr int BCAP    = 12288;             // staging capacity per bucket
constexpr int ZSPLIT  = 8;                 // sub-blocks per bucket in zagg

__device__ __forceinline__ int gdiv(int v, int npg, float inv) {
    int g = __float2int_rz((float)v * inv);
    int r = v - g * npg;
    if (r < 0) --g; else if (r >= npg) ++g;
    return g;
}

// Pass 1: LDS-binned bucket staging. code = (dst_local << 20) | src (src < 2^20).
__global__ __launch_bounds__(256)
void binfill_kernel(const int* __restrict__ src, const int* __restrict__ dst,
                    int* __restrict__ bcnt, int* __restrict__ binned, int E) {
    __shared__ int hist[NBMAX], hexcl[NBMAX], gbase[NBMAX], hpos[NBMAX], tmp[NBMAX];
    __shared__ int sorted[ECHUNK];
    __shared__ unsigned char bsorted[ECHUNK];
    int t = threadIdx.x;
    hist[t] = 0; hpos[t] = 0;
    __syncthreads();
    int e0 = blockIdx.x * ECHUNK;
    int cnt = min(ECHUNK, E - e0);
    for (int i = t; i < cnt; i += 256)
        atomicAdd(&hist[dst[e0 + i] >> BSZ_LOG], 1);
    __syncthreads();
    tmp[t] = hist[t];
    __syncthreads();
    for (int d = 1; d < 256; d <<= 1) {
        int v = (t >= d) ? tmp[t - d] : 0;
        __syncthreads();
        tmp[t] += v;
        __syncthreads();
    }
    hexcl[t] = (t == 0) ? 0 : tmp[t - 1];
    int h = hist[t];
    gbase[t] = (h > 0) ? atomicAdd(&bcnt[t], h) : 0;
    __syncthreads();
    for (int i = t; i < cnt; i += 256) {
        int s = src[e0 + i], d = dst[e0 + i];
        int b = d >> BSZ_LOG;
        int code = ((d & (BSZ - 1)) << 20) | s;
        int sp = hexcl[b] + atomicAdd(&hpos[b], 1);
        sorted[sp] = code;
        bsorted[sp] = (unsigned char)b;
    }
    __syncthreads();
    for (int i = t; i < cnt; i += 256) {
        int b = bsorted[i];
        binned[(size_t)b * BCAP + gbase[b] + (i - hexcl[b])] = sorted[i];
    }
}

// Block-reduce sum of bcnt[0..b) -> returned in sums[0] (all threads see it).
__device__ __forceinline__ int prefix_before(const int* __restrict__ bcnt,
                                             int b, int* sums) {
    int t = threadIdx.x;
    sums[t] = (t < b) ? bcnt[t] : 0;
    __syncthreads();
    for (int d = 128; d > 0; d >>= 1) {
        if (t < d) sums[t] += sums[t + d];
        __syncthreads();
    }
    int r = sums[0];
    __syncthreads();
    return r;
}

// Per bucket: LDS node histogram + scan -> coalesced off[] and dis[] writes.
__global__ __launch_bounds__(256)
void csr_off_kernel(const int* __restrict__ binned, const int* __restrict__ bcnt,
                    int* __restrict__ off, float* __restrict__ dis, int n, int E) {
    __shared__ int hist[BSZ];
    __shared__ int lstart[BSZ];
    __shared__ int partial[256];
    int b = blockIdx.x, t = threadIdx.x;
    int nb0 = b << BSZ_LOG;
    int nn = min(BSZ, n - nb0);
    int m = bcnt[b];
    int bs = prefix_before(bcnt, b, partial);
    const int* bp = binned + (size_t)b * BCAP;
    for (int i = t; i < BSZ; i += 256) hist[i] = 0;
    __syncthreads();
    for (int i = t; i < m; i += 256)
        atomicAdd(&hist[bp[i] >> 20], 1);
    __syncthreads();
    int a0 = hist[2 * t], a1 = hist[2 * t + 1];
    partial[t] = a0 + a1;
    __syncthreads();
    for (int d = 1; d < 256; d <<= 1) {
        int v = (t >= d) ? partial[t - d] : 0;
        __syncthreads();
        partial[t] += v;
        __syncthreads();
    }
    int base = (t == 0) ? 0 : partial[t - 1];
    lstart[2 * t] = base;
    lstart[2 * t + 1] = base + a0;
    __syncthreads();
    for (int i = t; i < nn; i += 256) {
        off[nb0 + i] = bs + lstart[i];
        dis[nb0 + i] = rsqrtf((float)hist[i] + 1.0f);   // +1 = self-loop
    }
    if (b == 0 && t == 0) off[n] = E;
}

// Per bucket: scatter {src | g<<20, w} to exact CSR positions (L2-local window).
__global__ __launch_bounds__(256)
void bucket_scatter_kernel(const int* __restrict__ binned, const int* __restrict__ bcnt,
                           const float* __restrict__ dis,
                           const int* __restrict__ npg_p, int2* __restrict__ ew, int n) {
    __shared__ int lstart[BSZ];
    __shared__ int lpos[BSZ];
    __shared__ float ldis[BSZ];
    __shared__ int partial[256];
    int b = blockIdx.x, t = threadIdx.x;
    int nb0 = b << BSZ_LOG;
    int nn = min(BSZ, n - nb0);
    int m = bcnt[b];
    int e0 = prefix_before(bcnt, b, partial);
    int npg = npg_p[0];
    float inv = 1.0f / (float)npg;
    const int* bp = binned + (size_t)b * BCAP;
    for (int i = t; i < BSZ; i += 256) {
        lstart[i] = 0; lpos[i] = 0;
        ldis[i] = (i < nn) ? dis[nb0 + i] : 0.f;
    }
    __syncthreads();
    for (int i = t; i < m; i += 256)
        atomicAdd(&lstart[bp[i] >> 20], 1);
    __syncthreads();
    int a0 = lstart[2 * t], a1 = lstart[2 * t + 1];
    partial[t] = a0 + a1;
    __syncthreads();
    for (int d = 1; d < 256; d <<= 1) {
        int v = (t >= d) ? partial[t - d] : 0;
        __syncthreads();
        partial[t] += v;
        __syncthreads();
    }
    int base = (t == 0) ? 0 : partial[t - 1];
    lstart[2 * t] = base;
    lstart[2 * t + 1] = base + a0;
    __syncthreads();
    for (int i = t; i < m; i += 256) {
        int code = bp[i];
        int dl = code >> 20, s = code & 0xFFFFF;
        float w = dis[s] * ldis[dl];
        int g = gdiv(s, npg, inv);
        int p = e0 + lstart[dl] + atomicAdd(&lpos[dl], 1);
        ew[p] = make_int2(s | (g << 20), __float_as_int(w));
    }
}

// ---- shfl-broadcast edge-gather core (TPN lanes per node) -----------------
template <int TPN, bool USE_G>
__device__ __forceinline__ float4
edge_loop(const float4* __restrict__ hp, const int2* __restrict__ ew,
          int e0, int e1, int q, float4 acc) {
    int deg = e1 - e0;
    int nfull = deg / TPN;
    int r = deg - nfull * TPN;
    int idx = e0 + q;
    int2 a = make_int2(0, 0);
    if (idx < e1) a = ew[idx];
    for (int c = 0; c < nfull; ++c) {
        int nidx = idx + (c + 1) * TPN;
        int2 an = make_int2(0, 0);
        if (nidx < e1) an = ew[nidx];
#pragma unroll
        for (int k = 0; k < TPN; ++k) {
            int ax = __shfl(a.x, k, TPN);
            float w = __int_as_float(__shfl(a.y, k, TPN));
            int row = USE_G ? (int)(((unsigned)ax) >> 20) : (ax & 0xFFFFF);
            float4 v = hp[(size_t)row * TPN + q];
            acc.x += w * v.x; acc.y += w * v.y; acc.z += w * v.z; acc.w += w * v.w;
        }
        a = an;
    }
    for (int k = 0; k < r; ++k) {
        int ax = __shfl(a.x, k, TPN);
        float w = __int_as_float(__shfl(a.y, k, TPN));
        int row = USE_G ? (int)(((unsigned)ax) >> 20) : (ax & 0xFFFFF);
        float4 v = hp[(size_t)row * TPN + q];
        acc.x += w * v.x; acc.y += w * v.y; acc.z += w * v.z; acc.w += w * v.w;
    }
    return acc;
}

// Layer 1 + W2 fused: agg x (16-wide, 4 lanes/node); phase-B h1=relu(.@W1+b1)
// into LDS; phase-C t2 = h1@W2 (register-blocked) written straight to global.
__global__ __launch_bounds__(256)
void l1w2_kernel(const float* __restrict__ x, const float* __restrict__ dis,
                 const int* __restrict__ off, const int2* __restrict__ ew,
                 const float* __restrict__ W1, const float* __restrict__ b1,
                 const float* __restrict__ W2, float* __restrict__ t2, int n) {
    __shared__ float accs[64 * 20];   // stride 20 (float4-aligned)
    __shared__ float hl[64 * 68];     // stride 68 (float4-aligned)
    __shared__ float Wl[16 * 64];
    __shared__ float bl[64];
    int t = threadIdx.x;
    for (int i = t; i < 16 * 64; i += 256) Wl[i] = W1[i];
    if (t < 64) bl[t] = b1[t];

    int q = t & 3, ln = t >> 2;
    int node = blockIdx.x * 64 + ln;
    const float4* xp = (const float4*)x;
    float4 acc = make_float4(0.f, 0.f, 0.f, 0.f);
    if (node < n) {
        float di = dis[node], d2 = di * di;
        float4 v = xp[(size_t)node * 4 + q];
        acc.x = d2 * v.x; acc.y = d2 * v.y; acc.z = d2 * v.z; acc.w = d2 * v.w;
        acc = edge_loop<4, false>(xp, ew, off[node], off[node + 1], q, acc);
    }
    accs[ln * 20 + q * 4 + 0] = acc.x; accs[ln * 20 + q * 4 + 1] = acc.y;
    accs[ln * 20 + q * 4 + 2] = acc.z; accs[ln * 20 + q * 4 + 3] = acc.w;
    __syncthreads();

    // Phase B: h1 row (64-wide) into LDS; register-blocked over 16 nodes.
    {
        int j = t & 63;
        int i0 = (t >> 6) * 16;
        float w1c[16];
#pragma unroll
        for (int k = 0; k < 16; ++k) w1c[k] = Wl[k * 64 + j];
        float bj = bl[j];
        const float4* ac4 = (const float4*)accs;
#pragma unroll
        for (int ii = 0; ii < 16; ++ii) {
            int i = i0 + ii;
            float s = bj;
#pragma unroll
            for (int m = 0; m < 4; ++m) {
                float4 av = ac4[i * 5 + m];
                s += av.x * w1c[4 * m] + av.y * w1c[4 * m + 1]
                   + av.z * w1c[4 * m + 2] + av.w * w1c[4 * m + 3];
            }
            hl[i * 68 + j] = fmaxf(s, 0.f);
        }
    }
    __syncthreads();

    // Phase C: t2 = h1 @ W2 (64->32), register-blocked: W2 column halves in
    // VGPRs amortized over 8 nodes; hl via broadcast float4 LDS reads.
    {
        int base = blockIdx.x * 64;
        int c = t & 31;
        int i0 = (t >> 5) * 8;
        float sa[8];
#pragma unroll
        for (int ii = 0; ii < 8; ++ii) sa[ii] = 0.f;
        const float4* hl4 = (const float4*)hl;
#pragma unroll
        for (int kh = 0; kh < 2; ++kh) {
            float w2c[32];
#pragma unroll
            for (int k = 0; k < 32; ++k) w2c[k] = W2[(kh * 32 + k) * 32 + c];
#pragma unroll
            for (int ii = 0; ii < 8; ++ii) {
                int i = i0 + ii;
#pragma unroll
                for (int m = 0; m < 8; ++m) {
                    float4 hv = hl4[i * 17 + kh * 8 + m];
                    sa[ii] += hv.x * w2c[4 * m] + hv.y * w2c[4 * m + 1]
                            + hv.z * w2c[4 * m + 2] + hv.w * w2c[4 * m + 3];
                }
            }
        }
#pragma unroll
        for (int ii = 0; ii < 8; ++ii) {
            int nd = base + i0 + ii;
            if (nd < n) t2[(size_t)nd * 32 + c] = sa[ii];
        }
    }
}

// Aggregate WD-wide features through CSR; WD/4 lanes per node.
template <int WD>
__global__ __launch_bounds__(256)
void agg_kernel(const float* __restrict__ h, const float* __restrict__ dis,
                const int* __restrict__ off, const int2* __restrict__ ew,
                const float* __restrict__ b, float* __restrict__ out, int n) {
    constexpr int TPN = WD / 4;
    constexpr int NPB = 256 / TPN;
    int t = threadIdx.x;
    int q = t % TPN, ln = t / TPN;
    int node = blockIdx.x * NPB + ln;
    if (node >= n) return;
    const float4* hp = (const float4*)h;
    float di = dis[node], d2 = di * di;
    float4 v = hp[(size_t)node * TPN + q];
    float4 acc;
    acc.x = d2 * v.x; acc.y = d2 * v.y; acc.z = d2 * v.z; acc.w = d2 * v.w;
    acc = edge_loop<TPN, false>(hp, ew, off[node], off[node + 1], q, acc);
    float4 bb = ((const float4*)b)[q];
    float4 o;
    o.x = acc.x + bb.x; o.y = acc.y + bb.y; o.z = acc.z + bb.z; o.w = acc.w + bb.w;
    ((float4*)out)[(size_t)node * TPN + q] = o;
}

// zagg: per (bucket, split): accumulate z-sums edge-major. Bucket spans <= 2
// graphs; edge's dst-graph = (CSR pos < P) ? g0 : g0+1. Block reduce; atomics.
__global__ __launch_bounds__(256)
void zagg_kernel(const float* __restrict__ t2, const float* __restrict__ dis,
                 const int* __restrict__ off, const int2* __restrict__ ew,
                 const int* __restrict__ npg_p, float* __restrict__ zsum, int n) {
    __shared__ float4 red0[256];
    __shared__ float4 red1[256];
    int blk = blockIdx.x;
    int b = blk / ZSPLIT, s = blk % ZSPLIT;
    int t = threadIdx.x, q = t & 7, r = t >> 3;
    int npg = npg_p[0];
    int nb0 = b << BSZ_LOG;
    int nn = min(BSZ, n - nb0);
    int g0 = nb0 / npg;
    int nodeB = min((g0 + 1) * npg - nb0, nn);   // local boundary node
    int e0 = off[nb0], e1 = off[nb0 + nn];
    int P  = off[nb0 + nodeB];
    int m = e1 - e0;
    const float4* hp = (const float4*)t2;

    float4 a0 = make_float4(0.f, 0.f, 0.f, 0.f);
    float4 a1 = make_float4(0.f, 0.f, 0.f, 0.f);
    int i0 = (int)((long long)m * s / ZSPLIT);
    int i1 = (int)((long long)m * (s + 1) / ZSPLIT);
    for (int i = i0 + r; i < i1; i += 32) {
        int e = e0 + i;
        int2 aa = ew[e];
        float w = __int_as_float(aa.y);
        int src = aa.x & 0xFFFFF;
        float4 v = hp[(size_t)src * 8 + q];
        if (e < P) {
            a0.x += w * v.x; a0.y += w * v.y; a0.z += w * v.z; a0.w += w * v.w;
        } else {
            a1.x += w * v.x; a1.y += w * v.y; a1.z += w * v.z; a1.w += w * v.w;
        }
    }
    int j0 = nn * s / ZSPLIT, j1 = nn * (s + 1) / ZSPLIT;
    for (int i = j0 + r; i < j1; i += 32) {
        int node = nb0 + i;
        float di = dis[node], d2 = di * di;
        float4 v = hp[(size_t)node * 8 + q];
        if (i < nodeB) {
            a0.x += d2 * v.x; a0.y += d2 * v.y; a0.z += d2 * v.z; a0.w += d2 * v.w;
        } else {
            a1.x += d2 * v.x; a1.y += d2 * v.y; a1.z += d2 * v.z; a1.w += d2 * v.w;
        }
    }
    red0[t] = a0; red1[t] = a1;
    __syncthreads();
    for (int d = 128; d >= 8; d >>= 1) {
        if (t < d) {
            float4 u = red0[t], v = red0[t + d];
            u.x += v.x; u.y += v.y; u.z += v.z; u.w += v.w;
            red0[t] = u;
            u = red1[t]; v = red1[t + d];
            u.x += v.x; u.y += v.y; u.z += v.z; u.w += v.w;
            red1[t] = u;
        }
        __syncthreads();
    }
    if (t < 8) {
        float4 v = red0[t];
        atomicAdd(&zsum[g0 * 32 + t * 4 + 0], v.x);
        atomicAdd(&zsum[g0 * 32 + t * 4 + 1], v.y);
        atomicAdd(&zsum[g0 * 32 + t * 4 + 2], v.z);
        atomicAdd(&zsum[g0 * 32 + t * 4 + 3], v.w);
    } else if (t < 16 && nodeB < nn) {
        float4 v = red1[t - 8];
        atomicAdd(&zsum[(g0 + 1) * 32 + (t - 8) * 4 + 0], v.x);
        atomicAdd(&zsum[(g0 + 1) * 32 + (t - 8) * 4 + 1], v.y);
        atomicAdd(&zsum[(g0 + 1) * 32 + (t - 8) * 4 + 2], v.z);
        atomicAdd(&zsum[(g0 + 1) * 32 + (t - 8) * 4 + 3], v.w);
    }
}

// z[g][c] = zsum[g][c]/npg + b2[c]
__global__ __launch_bounds__(256)
void zred_kernel(const float* __restrict__ zsum, const float* __restrict__ b2,
                 const int* __restrict__ npg_p, float* __restrict__ Z, int n) {
    int npg = npg_p[0];
    int G = n / npg;
    float inv = 1.0f / (float)npg;
    for (int i = blockIdx.x * 256 + threadIdx.x; i < G * 32; i += gridDim.x * 256)
        Z[i] = zsum[i] * inv + b2[i & 31];
}

// Decoder fused: aggregate 32-wide z rows from global (L1-resident); dense
// phases REGISTER-BLOCKED: weight column in VGPRs, broadcast float4 LDS reads.
__global__ __launch_bounds__(256)
void dec1v4_kernel(const float* __restrict__ Z, const float* __restrict__ dis,
                   const int* __restrict__ off, const int2* __restrict__ ew,
                   const int* __restrict__ npg_p, const float* __restrict__ W3,
                   const float* __restrict__ b3, const float* __restrict__ W4,
                   float* __restrict__ t4, int n) {
    __shared__ float zacc[32 * 36];   // stride 36 (float4-aligned)
    __shared__ float hl[32 * 68];     // stride 68 (float4-aligned)
    int t = threadIdx.x;
    int npg = npg_p[0];
    float inv = 1.0f / (float)npg;
    int q = t & 7, ln = t >> 3;          // 8 lanes/node, 32 nodes/block
    int base = blockIdx.x * 32;
    int node = base + ln;
    const float4* zp = (const float4*)Z;

    float4 acc = make_float4(0.f, 0.f, 0.f, 0.f);
    if (node < n) {
        float di = dis[node], d2 = di * di;
        int gi = gdiv(node, npg, inv);
        float4 v = zp[(size_t)gi * 8 + q];
        acc.x = d2 * v.x; acc.y = d2 * v.y; acc.z = d2 * v.z; acc.w = d2 * v.w;
        acc = edge_loop<8, true>(zp, ew, off[node], off[node + 1], q, acc);
    }
    zacc[ln * 36 + q * 4 + 0] = acc.x;
    zacc[ln * 36 + q * 4 + 1] = acc.y;
    zacc[ln * 36 + q * 4 + 2] = acc.z;
    zacc[ln * 36 + q * 4 + 3] = acc.w;
    __syncthreads();

    // B1: h = relu(zacc @ W3 + b3). 64 cols x 4 row-groups of 8 nodes.
    {
        int j = t & 63;
        int i0 = (t >> 6) * 8;
        float w3c[32];
#pragma unroll
        for (int k = 0; k < 32; ++k) w3c[k] = W3[k * 64 + j];
        float bj = b3[j];
        const float4* za4 = (const float4*)zacc;
#pragma unroll
        for (int ii = 0; ii < 8; ++ii) {
            int i = i0 + ii;
            float s = bj;
#pragma unroll
            for (int m = 0; m < 8; ++m) {
                float4 zv = za4[i * 9 + m];
                s += zv.x * w3c[4 * m] + zv.y * w3c[4 * m + 1]
                   + zv.z * w3c[4 * m + 2] + zv.w * w3c[4 * m + 3];
            }
            hl[i * 68 + j] = fmaxf(s, 0.f);
        }
    }
    __syncthreads();

    // B2: t4 = hl @ W4 (64->16). 16 cols x 16 rows; each thread 2 nodes.
    {
        int c = t & 15;
        int i0 = t >> 4;
        int i1 = i0 + 16;
        const float4* hl4 = (const float4*)hl;
        float s0 = 0.f, s1 = 0.f;
#pragma unroll
        for (int kh = 0; kh < 2; ++kh) {
            float w4c[32];
#pragma unroll
            for (int k = 0; k < 32; ++k) w4c[k] = W4[(kh * 32 + k) * 16 + c];
#pragma unroll
            for (int m = 0; m < 8; ++m) {
                float4 h0 = hl4[i0 * 17 + kh * 8 + m];
                float4 h1 = hl4[i1 * 17 + kh * 8 + m];
                s0 += h0.x * w4c[4 * m] + h0.y * w4c[4 * m + 1]
                    + h0.z * w4c[4 * m + 2] + h0.w * w4c[4 * m + 3];
                s1 += h1.x * w4c[4 * m] + h1.y * w4c[4 * m + 1]
                    + h1.z * w4c[4 * m + 2] + h1.w * w4c[4 * m + 3];
            }
        }
        int nd0 = base + i0, nd1 = base + i1;
        if (nd0 < n) t4[(size_t)nd0 * 16 + c] = s0;
        if (nd1 < n) t4[(size_t)nd1 * 16 + c] = s1;
    }
}

extern "C" void kernel_launch(void* const* d_in, const int* in_sizes, int n_in,
                              void* d_out, int out_size, void* d_ws, size_t ws_size,
                              hipStream_t stream) {
    const float* x     = (const float*)d_in[0];
    const int*   ei    = (const int*)d_in[1];
    const int*   npg   = (const int*)d_in[3];
    const float* W1 = (const float*)d_in[4];
    const float* b1 = (const float*)d_in[5];
    const float* W2 = (const float*)d_in[6];
    const float* b2 = (const float*)d_in[7];
    const float* W3 = (const float*)d_in[8];
    const float* b3 = (const float*)d_in[9];
    const float* W4 = (const float*)d_in[10];
    const float* b4 = (const float*)d_in[11];
    float* out = (float*)d_out;

    int n = in_sizes[0] / 16;
    int E = in_sizes[1] / 2;
    const int* srcp = ei;
    const int* dstp = ei + E;

    char* w = (char*)d_ws;
    auto alloc = [&](size_t bytes) {
        char* p = w;
        w += (bytes + 255) & ~(size_t)255;
        return p;
    };
    float* dis    = (float*)alloc((size_t)n * 4);
    int*   off    = (int*)alloc(((size_t)n + 1) * 4);
    int*   binned = (int*)alloc((size_t)NBMAX * BCAP * 4);
    int2*  ew     = (int2*)alloc((size_t)E * 8);
    float* B      = (float*)alloc((size_t)n * 32 * 4);  // t2, later t4
    float* Z      = (float*)alloc((size_t)4096 * 32 * 4);
    float* zsum   = (float*)alloc((size_t)4096 * 32 * 4);
    int*   bcnt   = (int*)alloc((size_t)NBMAX * 4);

    int nbuck = (n + BSZ - 1) / BSZ;
    int nbin  = (E + ECHUNK - 1) / ECHUNK;

    // ---- CSR build ----
    hipMemsetAsync(bcnt, 0, (size_t)NBMAX * 4, stream);
    hipMemsetAsync(zsum, 0, (size_t)4096 * 32 * 4, stream);
    binfill_kernel<<<nbin, 256, 0, stream>>>(srcp, dstp, bcnt, binned, E);
    csr_off_kernel<<<nbuck, 256, 0, stream>>>(binned, bcnt, off, dis, n, E);
    bucket_scatter_kernel<<<nbuck, 256, 0, stream>>>(binned, bcnt, dis, npg, ew, n);

    // encode
    l1w2_kernel<<<(n + 63) / 64, 256, 0, stream>>>(x, dis, off, ew, W1, b1, W2, B, n);
    zagg_kernel<<<nbuck * ZSPLIT, 256, 0, stream>>>(B, dis, off, ew, npg, zsum, n);
    zred_kernel<<<16, 256, 0, stream>>>(zsum, b2, npg, Z, n);

    // decode
    dec1v4_kernel<<<(n + 31) / 32, 256, 0, stream>>>(Z, dis, off, ew, npg, W3, b3, W4, B, n);
    agg_kernel<16><<<(n + 63) / 64, 256, 0, stream>>>(B, dis, off, ew, b4, out, n);
}